// Round 10
// baseline (217.108 us; speedup 1.0000x reference)
//
#include <hip/hip_runtime.h>
#include <hip/hip_bf16.h>
#include <math.h>

typedef __bf16 bf16;
typedef __bf16 bf16x8 __attribute__((ext_vector_type(8)));
typedef __bf16 bf16x4 __attribute__((ext_vector_type(4)));
typedef float f32x4 __attribute__((ext_vector_type(4)));
typedef unsigned int u32;
typedef u32 u32x4 __attribute__((ext_vector_type(4)));

#define S_ 4096
#define D_ 1024
#define H_ 16
#define HD_ 64
#define N3_ 3072
#define NSPLIT 4

// async global->LDS 16B (m97 pattern)
typedef const __attribute__((address_space(1))) void* gas1_t;
typedef __attribute__((address_space(3))) void* las3_t;
static __device__ __forceinline__ void g2l16(const void* g, void* l) {
  __builtin_amdgcn_global_load_lds((gas1_t)g, (las3_t)l, 16, 0, 0);
}

static __device__ __forceinline__ u32 fbits(float x) {
  union { float f; u32 u; } c; c.f = x; return c.u;
}

// ---------------- fused prep: cvt x -> bf16, transpose both weights ----------------
__global__ __launch_bounds__(256) void prep_kernel(const float* __restrict__ x,
                                                   bf16* __restrict__ xb,
                                                   const float* __restrict__ w_qkv,
                                                   bf16* __restrict__ wqkvT,
                                                   const float* __restrict__ w_proj,
                                                   bf16* __restrict__ wprojT) {
  __shared__ float t[32][33];
  const int b = blockIdx.x;
  if (b < 4096) {
    int i = (b * 256 + threadIdx.x) * 4;
    float4 v = *(const float4*)(x + i);
    bf16x4 o;
    o.x = (bf16)v.x; o.y = (bf16)v.y; o.z = (bf16)v.z; o.w = (bf16)v.w;
    *(bf16x4*)(xb + i) = o;
    return;
  }
  const float* in; bf16* outp; int ldin, bx, by;
  if (b < 7168) { int b2 = b - 4096; in = w_qkv;  outp = wqkvT;  ldin = N3_; bx = (b2 % 96) * 32; by = (b2 / 96) * 32; }
  else          { int b3 = b - 7168; in = w_proj; outp = wprojT; ldin = D_;  bx = (b3 % 32) * 32; by = (b3 / 32) * 32; }
  const int tx = threadIdx.x & 31, ty = threadIdx.x >> 5;
#pragma unroll
  for (int i = 0; i < 4; ++i)
    t[ty + i * 8][tx] = in[(size_t)(by + ty + i * 8) * ldin + bx + tx];
  __syncthreads();
#pragma unroll
  for (int i = 0; i < 4; ++i)
    outp[(size_t)(bx + ty + i * 8) * D_ + by + tx] = (bf16)t[tx][ty + i * 8];
}

// ---------------- bf16 GEMM (m97 pattern): C = A * Bt^T + bias ----------------
// If vF != nullptr (QKV mode): Q cols scaled by qscale, V cols (gn>=2048)
// written directly in MFMA-fragment layout vF[hh][kb64][c][n][lane][8].
template <int BN>
__global__ __launch_bounds__(256) void gemm_bt(const bf16* __restrict__ A,
                                               const bf16* __restrict__ Bt,
                                               const float* __restrict__ bias,
                                               bf16* __restrict__ outb,
                                               float* __restrict__ outf,
                                               bf16* __restrict__ vF,
                                               int M, int N, int K,
                                               int qlim, float qscale) {
  constexpr int NT = BN / 32;  // n-tiles per wave
  __shared__ bf16 sA[128 * 32];
  __shared__ bf16 sB[BN * 32];
  const int tid = threadIdx.x;
  const int wave = tid >> 6, lane = tid & 63;
  const int col = lane & 15, quad = lane >> 4;
  const int wm = (wave & 1) * 64, wn = (wave >> 1) * (BN / 2);
  const long bm = (long)blockIdx.x * 128, bn = (long)blockIdx.y * BN;
  const int srow = tid >> 2;        // 0..63
  const int soff = (tid & 3) * 8;   // elem in 32-elem row

  f32x4 acc[4][NT] = {};

  for (int kb = 0; kb < K; kb += 32) {
    __syncthreads();
    g2l16(A + (bm + srow) * (long)K + kb + soff,      &sA[tid * 8]);
    g2l16(A + (bm + 64 + srow) * (long)K + kb + soff, &sA[2048 + tid * 8]);
#pragma unroll
    for (int i = 0; i < BN / 64; ++i)
      g2l16(Bt + (bn + i * 64 + srow) * (long)K + kb + soff, &sB[i * 2048 + tid * 8]);
    __syncthreads();

    bf16x8 af[4], bfr[NT];
#pragma unroll
    for (int t = 0; t < 4; ++t)
      af[t] = *(const bf16x8*)(&sA[(wm + t * 16 + col) * 32 + quad * 8]);
#pragma unroll
    for (int t = 0; t < NT; ++t)
      bfr[t] = *(const bf16x8*)(&sB[(wn + t * 16 + col) * 32 + quad * 8]);
#pragma unroll
    for (int mt = 0; mt < 4; ++mt)
#pragma unroll
      for (int nt = 0; nt < NT; ++nt)
        acc[mt][nt] = __builtin_amdgcn_mfma_f32_16x16x32_bf16(af[mt], bfr[nt], acc[mt][nt], 0, 0, 0);
  }

#pragma unroll
  for (int mt = 0; mt < 4; ++mt) {
#pragma unroll
    for (int nt = 0; nt < NT; ++nt) {
      long gn = bn + wn + nt * 16 + col;
      float bv = bias ? bias[gn] : 0.f;
      if (vF && gn >= 2 * D_) {  // V column -> fragment-layout store
        int hd = (int)gn - 2 * D_;
        int hh2 = hd >> 6, nn = (hd >> 4) & 3, colp = hd & 15;
        long key0 = bm + wm + mt * 16 + quad * 4;   // 4-aligned, no 64-crossing
        int kb64 = (int)(key0 >> 6), kl = (int)(key0 & 63);
        int cc = kl >> 5, qp2 = (kl >> 3) & 3, j0 = kl & 7;  // j0 in {0,4}
        bf16x4 vv;
#pragma unroll
        for (int i = 0; i < 4; ++i) vv[i] = (bf16)(acc[mt][nt][i] + bv);
        *(bf16x4*)(&vF[((((size_t)(hh2 * 64 + kb64) * 2 + cc) * 4 + nn) * 64 +
                        qp2 * 16 + colp) * 8 + j0]) = vv;
      } else {
        float sc = (gn < qlim) ? qscale : 1.0f;
#pragma unroll
        for (int i = 0; i < 4; ++i) {
          long gm = bm + wm + mt * 16 + quad * 4 + i;
          float v = (acc[mt][nt][i] + bv) * sc;
          if (outf) outf[gm * N + gn] = v;
          else      outb[gm * N + gn] = (bf16)v;
        }
      }
    }
  }
}

// ---------------- repack K rows -> fragment layout kF ----------------
// kF[hh][kb64][t][half][lane(col,quad)][8] = K[kb64*64 + row(t,col)][hh*64 + half*32 + quad*8 +j]
// row(t,col) = (t>>1)*32 + (t&1)*4 + (col>>2)*8 + (col&3)   (the permuted QK A-frag map)
// grid (H_, 64), block 256: LDS-staged (coalesced read), coalesced 16B/lane write.
__global__ __launch_bounds__(256) void repackK(const bf16* __restrict__ qkv,
                                               bf16* __restrict__ kF) {
  __shared__ bf16 sK[64 * 72];
  const int hh = blockIdx.x, kb64 = blockIdx.y;
  const int tid = threadIdx.x;
  const int srow = tid >> 2, sc = (tid & 3) * 16;
  const bf16* src = qkv + (size_t)(kb64 * 64 + srow) * N3_ + D_ + hh * HD_ + sc;
  *(int4*)(&sK[srow * 72 + sc])     = *(const int4*)src;
  *(int4*)(&sK[srow * 72 + sc + 8]) = *(const int4*)(src + 8);
  __syncthreads();
  const int lane = tid & 63, col = lane & 15, quad = lane >> 4;
  const int t = tid >> 6;  // wave = t
  const int row = (t >> 1) * 32 + (t & 1) * 4 + (col >> 2) * 8 + (col & 3);
  bf16* dst = kF + ((size_t)(hh * 64 + kb64) * 8 + t * 2) * 512 + lane * 8;
  *(bf16x8*)(dst)       = *(const bf16x8*)(&sK[row * 72 + quad * 8]);
  *(bf16x8*)(dst + 512) = *(const bf16x8*)(&sK[row * 72 + 32 + quad * 8]);
}

// ---------------- causal flash attention: LDS-free, barrier-free ----------------
// grid (H, 32, 4), block 256 = 4 independent waves; 32 q-rows/wave (two 16-row
// subtiles); 64-key chunks; K/V fragments loaded DIRECTLY global->VGPR from the
// frag-layout kF/vF (each frag = 64 lanes x 16B contiguous -> one coalesced
// global_load_dwordx4). No __shared__, no __syncthreads: waves schedule freely,
// loads pipeline across iterations. No-max softmax; l via ones-MFMA; exact
// 4-way K-split combined by addition.
__global__ __launch_bounds__(256) void attn_kernel(const bf16* __restrict__ qkv,
                                                   const bf16* __restrict__ kF,
                                                   const bf16* __restrict__ vF,
                                                   bf16* __restrict__ Opart,
                                                   float* __restrict__ lws) {
  const int hh = blockIdx.x;
  const int qb = (int)(gridDim.y - 1 - blockIdx.y);  // heavy blocks dispatch first
  const int sp = blockIdx.z;
  const int tid = threadIdx.x;
  const int wave = tid >> 6, lane = tid & 63;
  const int col = lane & 15, quad = lane >> 4;
  const int qbase = qb * 128 + wave * 32;

  // Q fragments (B-operand layout) for the two 16-row subtiles
  const bf16* qp0 = qkv + (size_t)(qbase + col) * N3_ + hh * HD_;
  bf16x8 aq[2][2];
  aq[0][0] = *(const bf16x8*)(qp0 + quad * 8);
  aq[0][1] = *(const bf16x8*)(qp0 + 32 + quad * 8);
  aq[1][0] = *(const bf16x8*)(qp0 + 16 * N3_ + quad * 8);
  aq[1][1] = *(const bf16x8*)(qp0 + 16 * N3_ + 32 + quad * 8);

  bf16x8 ones;
#pragma unroll
  for (int j = 0; j < 8; ++j) ones[j] = (bf16)1.0f;

  f32x4 acc[2][4] = {};
  f32x4 acc_l[2] = {};

  const int niter = 2 * (qb + 1);
  const int bse = niter >> 2, rem = niter & 3;
  const int it0 = sp * bse + (sp < rem ? sp : rem);
  const int len = bse + (sp < rem ? 1 : 0);
  const int it1 = it0 + len;

  const bf16* kfp = kF + (size_t)(hh * 64 + it0) * 4096 + lane * 8;
  const bf16* vfp = vF + (size_t)(hh * 64 + it0) * 4096 + lane * 8;

  for (int j = it0; j < it1; ++j, kfp += 4096, vfp += 4096) {
    const int kb = j * 64;
    if (kb >= qbase + 32) break;  // causal: all later chunks masked (wave-uniform)
    const bool act0 = kb < qbase + 16;

    // --- S^T tiles: K-frags direct from kF ---
    f32x4 st[2][4];
#pragma unroll
    for (int t = 0; t < 4; ++t) {
      bf16x8 bk0 = *(const bf16x8*)(kfp + (t * 2) * 512);
      bf16x8 bk1 = *(const bf16x8*)(kfp + (t * 2 + 1) * 512);
      if (act0) {
        f32x4 z = {};
        z = __builtin_amdgcn_mfma_f32_16x16x32_bf16(bk0, aq[0][0], z, 0, 0, 0);
        st[0][t] = __builtin_amdgcn_mfma_f32_16x16x32_bf16(bk1, aq[0][1], z, 0, 0, 0);
      }
      f32x4 z = {};
      z = __builtin_amdgcn_mfma_f32_16x16x32_bf16(bk0, aq[1][0], z, 0, 0, 0);
      st[1][t] = __builtin_amdgcn_mfma_f32_16x16x32_bf16(bk1, aq[1][1], z, 0, 0, 0);
    }

    // --- p = exp2(s); causal mask only on diagonal chunks; perm-pack to bf16 ---
    bf16x8 pfrag[2][2];
#pragma unroll
    for (int s2 = 0; s2 < 2; ++s2) {
      if (s2 == 0 && !act0) continue;
      const int rowbase = qbase + 16 * s2;
      float p[4][4];
      if (kb + 63 <= rowbase) {  // fully unmasked
#pragma unroll
        for (int t = 0; t < 4; ++t)
#pragma unroll
          for (int r = 0; r < 4; ++r)
            p[t][r] = __builtin_amdgcn_exp2f(st[s2][t][r]);
      } else {                   // diagonal: causal mask
#pragma unroll
        for (int t = 0; t < 4; ++t)
#pragma unroll
          for (int r = 0; r < 4; ++r) {
            int key = kb + (t >> 1) * 32 + quad * 8 + (t & 1) * 4 + r;
            p[t][r] = (key > rowbase + col)
                          ? 0.f
                          : __builtin_amdgcn_exp2f(st[s2][t][r]);
          }
      }
#pragma unroll
      for (int c = 0; c < 2; ++c) {
        union { bf16x8 v; u32x4 u; } pu;
        pu.u[0] = __builtin_amdgcn_perm(fbits(p[2 * c][1]),     fbits(p[2 * c][0]),     0x07060302u);
        pu.u[1] = __builtin_amdgcn_perm(fbits(p[2 * c][3]),     fbits(p[2 * c][2]),     0x07060302u);
        pu.u[2] = __builtin_amdgcn_perm(fbits(p[2 * c + 1][1]), fbits(p[2 * c + 1][0]), 0x07060302u);
        pu.u[3] = __builtin_amdgcn_perm(fbits(p[2 * c + 1][3]), fbits(p[2 * c + 1][2]), 0x07060302u);
        pfrag[s2][c] = pu.v;
      }
    }

    // --- PV + l-accumulation: V-frags direct from vF ---
#pragma unroll
    for (int c = 0; c < 2; ++c) {
#pragma unroll
      for (int n = 0; n < 4; ++n) {
        bf16x8 bv = *(const bf16x8*)(vfp + (c * 4 + n) * 512);
        if (act0)
          acc[0][n] = __builtin_amdgcn_mfma_f32_16x16x32_bf16(pfrag[0][c], bv, acc[0][n], 0, 0, 0);
        acc[1][n] = __builtin_amdgcn_mfma_f32_16x16x32_bf16(pfrag[1][c], bv, acc[1][n], 0, 0, 0);
      }
      if (act0)
        acc_l[0] = __builtin_amdgcn_mfma_f32_16x16x32_bf16(pfrag[0][c], ones, acc_l[0], 0, 0, 0);
      acc_l[1] = __builtin_amdgcn_mfma_f32_16x16x32_bf16(pfrag[1][c], ones, acc_l[1], 0, 0, 0);
    }
  }

  // --- epilogue: write unnormalized O partial (bf16) and l partial (f32) ---
  bf16* Op = Opart + (size_t)sp * S_ * D_;
#pragma unroll
  for (int s2 = 0; s2 < 2; ++s2) {
    const int rowbase = qbase + 16 * s2;
    if (col == 0) {
#pragma unroll
      for (int r = 0; r < 4; ++r)
        lws[((size_t)sp * H_ + hh) * S_ + rowbase + quad * 4 + r] = acc_l[s2][r];
    }
#pragma unroll
    for (int n = 0; n < 4; ++n)
#pragma unroll
      for (int r = 0; r < 4; ++r)
        Op[(size_t)(rowbase + quad * 4 + r) * D_ + hh * HD_ + n * 16 + col] =
            (bf16)acc[s2][n][r];
  }
}

// ---------------- combine the four K-split partials ----------------
__global__ __launch_bounds__(256) void attn_combine(const bf16* __restrict__ Opart,
                                                    const float* __restrict__ lws,
                                                    bf16* __restrict__ outb) {
  int e = (blockIdx.x * 256 + threadIdx.x) * 8;
  int s = e >> 10;              // / D_
  int h = (e & (D_ - 1)) >> 6;  // head
  float l = 0.f;
#pragma unroll
  for (int sp = 0; sp < NSPLIT; ++sp) l += lws[((size_t)sp * H_ + h) * S_ + s];
  float inv = 1.0f / l;
  float o[8] = {};
#pragma unroll
  for (int sp = 0; sp < NSPLIT; ++sp) {
    bf16x8 a = *(const bf16x8*)(Opart + (size_t)sp * S_ * D_ + e);
#pragma unroll
    for (int j = 0; j < 8; ++j) o[j] += (float)a[j];
  }
  bf16x8 r;
#pragma unroll
  for (int j = 0; j < 8; ++j) r[j] = (bf16)(o[j] * inv);
  *(bf16x8*)(outb + e) = r;
}

// ---------------- host orchestration ----------------
extern "C" void kernel_launch(void* const* d_in, const int* in_sizes, int n_in,
                              void* d_out, int out_size, void* d_ws, size_t ws_size,
                              hipStream_t stream) {
  const float* x      = (const float*)d_in[0];
  const float* w_qkv  = (const float*)d_in[1];
  const float* b_qkv  = (const float*)d_in[2];
  const float* w_proj = (const float*)d_in[3];
  const float* b_proj = (const float*)d_in[4];
  float* out = (float*)d_out;

  // Buffer overlay (lifetimes verified):
  //   xb: prep->GEMM (x bf16); then repackK->attn (kF); then combine->proj (attn out)
  //   vF: GEMM epilogue writes, attn reads (old vT slot, 8 MB)
  bf16* xb     = (bf16*)d_ws;                       // 8 MB  (= kF = attn out)
  bf16* wqkvT  = xb + (size_t)S_ * D_;              // 6 MB
  bf16* wprojT = wqkvT + (size_t)N3_ * D_;          // 2 MB
  bf16* qkv    = wprojT + (size_t)D_ * D_;          // 24 MB (V cols unused)
  bf16* vF     = qkv + (size_t)S_ * N3_;            // 8 MB  frag-layout V
  bf16* Opart  = vF + (size_t)D_ * S_;              // 32 MB
  float* lws   = (float*)(Opart + (size_t)NSPLIT * S_ * D_);  // 1 MB
  bf16* kF     = xb;
  bf16* attn   = xb;

  const float QSCALE = 0.125f * 1.44269504088896f;  // 1/sqrt(64) * log2(e)

  prep_kernel<<<dim3(8192), 256, 0, stream>>>(x, xb, w_qkv, wqkvT, w_proj, wprojT);
  // QKV GEMM; Q cols pre-scaled; V cols written directly in frag layout to vF
  gemm_bt<128><<<dim3(S_ / 128, N3_ / 128), 256, 0, stream>>>(
      xb, wqkvT, b_qkv, qkv, nullptr, vF, S_, N3_, D_, D_, QSCALE);
  repackK<<<dim3(H_, S_ / 64), 256, 0, stream>>>(qkv, kF);
  attn_kernel<<<dim3(H_, S_ / 128, NSPLIT), 256, 0, stream>>>(qkv, kF, vF, Opart, lws);
  attn_combine<<<dim3((S_ * D_) / 2048), 256, 0, stream>>>(Opart, lws, attn);
  // proj GEMM: 128x64 tiles -> 512 blocks (2/CU) for latency hiding
  gemm_bt<64><<<dim3(S_ / 128, D_ / 64), 256, 0, stream>>>(
      attn, wprojT, b_proj, nullptr, out, nullptr, S_, D_, D_, 0, 1.0f);
}

// Round 11
// 216.650 us; speedup vs baseline: 1.0021x; 1.0021x over previous
//
#include <hip/hip_runtime.h>
#include <hip/hip_bf16.h>
#include <math.h>

typedef __bf16 bf16;
typedef __bf16 bf16x8 __attribute__((ext_vector_type(8)));
typedef __bf16 bf16x4 __attribute__((ext_vector_type(4)));
typedef float f32x4 __attribute__((ext_vector_type(4)));
typedef unsigned int u32;
typedef u32 u32x4 __attribute__((ext_vector_type(4)));

#define S_ 4096
#define D_ 1024
#define H_ 16
#define HD_ 64
#define N3_ 3072
#define NSPLIT 4

// async global->LDS 16B (m97 pattern)
typedef const __attribute__((address_space(1))) void* gas1_t;
typedef __attribute__((address_space(3))) void* las3_t;
static __device__ __forceinline__ void g2l16(const void* g, void* l) {
  __builtin_amdgcn_global_load_lds((gas1_t)g, (las3_t)l, 16, 0, 0);
}

static __device__ __forceinline__ u32 fbits(float x) {
  union { float f; u32 u; } c; c.f = x; return c.u;
}

// ---------------- fused prep: cvt x -> bf16, transpose both weights ----------------
__global__ __launch_bounds__(256) void prep_kernel(const float* __restrict__ x,
                                                   bf16* __restrict__ xb,
                                                   const float* __restrict__ w_qkv,
                                                   bf16* __restrict__ wqkvT,
                                                   const float* __restrict__ w_proj,
                                                   bf16* __restrict__ wprojT) {
  __shared__ float t[32][33];
  const int b = blockIdx.x;
  if (b < 4096) {
    int i = (b * 256 + threadIdx.x) * 4;
    float4 v = *(const float4*)(x + i);
    bf16x4 o;
    o.x = (bf16)v.x; o.y = (bf16)v.y; o.z = (bf16)v.z; o.w = (bf16)v.w;
    *(bf16x4*)(xb + i) = o;
    return;
  }
  const float* in; bf16* outp; int ldin, bx, by;
  if (b < 7168) { int b2 = b - 4096; in = w_qkv;  outp = wqkvT;  ldin = N3_; bx = (b2 % 96) * 32; by = (b2 / 96) * 32; }
  else          { int b3 = b - 7168; in = w_proj; outp = wprojT; ldin = D_;  bx = (b3 % 32) * 32; by = (b3 / 32) * 32; }
  const int tx = threadIdx.x & 31, ty = threadIdx.x >> 5;
#pragma unroll
  for (int i = 0; i < 4; ++i)
    t[ty + i * 8][tx] = in[(size_t)(by + ty + i * 8) * ldin + bx + tx];
  __syncthreads();
#pragma unroll
  for (int i = 0; i < 4; ++i)
    outp[(size_t)(bx + ty + i * 8) * D_ + by + tx] = (bf16)t[tx][ty + i * 8];
}

// ---------------- bf16 GEMM (m97 pattern): C = A * Bt^T + bias ----------------
// If vF != nullptr (QKV mode): Q cols scaled by qscale, V cols (gn>=2048)
// written directly in MFMA-fragment layout vF[hh][kb64][c][n][lane][8].
template <int BN>
__global__ __launch_bounds__(256) void gemm_bt(const bf16* __restrict__ A,
                                               const bf16* __restrict__ Bt,
                                               const float* __restrict__ bias,
                                               bf16* __restrict__ outb,
                                               float* __restrict__ outf,
                                               bf16* __restrict__ vF,
                                               int M, int N, int K,
                                               int qlim, float qscale) {
  constexpr int NT = BN / 32;  // n-tiles per wave
  __shared__ bf16 sA[128 * 32];
  __shared__ bf16 sB[BN * 32];
  const int tid = threadIdx.x;
  const int wave = tid >> 6, lane = tid & 63;
  const int col = lane & 15, quad = lane >> 4;
  const int wm = (wave & 1) * 64, wn = (wave >> 1) * (BN / 2);
  const long bm = (long)blockIdx.x * 128, bn = (long)blockIdx.y * BN;
  const int srow = tid >> 2;        // 0..63
  const int soff = (tid & 3) * 8;   // elem in 32-elem row

  f32x4 acc[4][NT] = {};

  for (int kb = 0; kb < K; kb += 32) {
    __syncthreads();
    g2l16(A + (bm + srow) * (long)K + kb + soff,      &sA[tid * 8]);
    g2l16(A + (bm + 64 + srow) * (long)K + kb + soff, &sA[2048 + tid * 8]);
#pragma unroll
    for (int i = 0; i < BN / 64; ++i)
      g2l16(Bt + (bn + i * 64 + srow) * (long)K + kb + soff, &sB[i * 2048 + tid * 8]);
    __syncthreads();

    bf16x8 af[4], bfr[NT];
#pragma unroll
    for (int t = 0; t < 4; ++t)
      af[t] = *(const bf16x8*)(&sA[(wm + t * 16 + col) * 32 + quad * 8]);
#pragma unroll
    for (int t = 0; t < NT; ++t)
      bfr[t] = *(const bf16x8*)(&sB[(wn + t * 16 + col) * 32 + quad * 8]);
#pragma unroll
    for (int mt = 0; mt < 4; ++mt)
#pragma unroll
      for (int nt = 0; nt < NT; ++nt)
        acc[mt][nt] = __builtin_amdgcn_mfma_f32_16x16x32_bf16(af[mt], bfr[nt], acc[mt][nt], 0, 0, 0);
  }

#pragma unroll
  for (int mt = 0; mt < 4; ++mt) {
#pragma unroll
    for (int nt = 0; nt < NT; ++nt) {
      long gn = bn + wn + nt * 16 + col;
      float bv = bias ? bias[gn] : 0.f;
      if (vF && gn >= 2 * D_) {  // V column -> fragment-layout store
        int hd = (int)gn - 2 * D_;
        int hh2 = hd >> 6, nn = (hd >> 4) & 3, colp = hd & 15;
        long key0 = bm + wm + mt * 16 + quad * 4;   // 4-aligned, no 64-crossing
        int kb64 = (int)(key0 >> 6), kl = (int)(key0 & 63);
        int cc = kl >> 5, qp2 = (kl >> 3) & 3, j0 = kl & 7;  // j0 in {0,4}
        bf16x4 vv;
#pragma unroll
        for (int i = 0; i < 4; ++i) vv[i] = (bf16)(acc[mt][nt][i] + bv);
        *(bf16x4*)(&vF[((((size_t)(hh2 * 64 + kb64) * 2 + cc) * 4 + nn) * 64 +
                        qp2 * 16 + colp) * 8 + j0]) = vv;
      } else {
        float sc = (gn < qlim) ? qscale : 1.0f;
#pragma unroll
        for (int i = 0; i < 4; ++i) {
          long gm = bm + wm + mt * 16 + quad * 4 + i;
          float v = (acc[mt][nt][i] + bv) * sc;
          if (outf) outf[gm * N + gn] = v;
          else      outb[gm * N + gn] = (bf16)v;
        }
      }
    }
  }
}

// ---------------- repack K rows -> fragment layout kF ----------------
// kF[hh][kb64][t][half][lane(col,quad)][8] = K[kb64*64 + row(t,col)][hh*64 + half*32 + quad*8 +j]
// row(t,col) = (t>>1)*32 + (t&1)*4 + (col>>2)*8 + (col&3)   (the permuted QK A-frag map)
// grid (H_, 64), block 256: LDS-staged (coalesced read), coalesced 16B/lane write.
__global__ __launch_bounds__(256) void repackK(const bf16* __restrict__ qkv,
                                               bf16* __restrict__ kF) {
  __shared__ bf16 sK[64 * 72];
  const int hh = blockIdx.x, kb64 = blockIdx.y;
  const int tid = threadIdx.x;
  const int srow = tid >> 2, sc = (tid & 3) * 16;
  const bf16* src = qkv + (size_t)(kb64 * 64 + srow) * N3_ + D_ + hh * HD_ + sc;
  *(int4*)(&sK[srow * 72 + sc])     = *(const int4*)src;
  *(int4*)(&sK[srow * 72 + sc + 8]) = *(const int4*)(src + 8);
  __syncthreads();
  const int lane = tid & 63, col = lane & 15, quad = lane >> 4;
  const int t = tid >> 6;  // wave = t
  const int row = (t >> 1) * 32 + (t & 1) * 4 + (col >> 2) * 8 + (col & 3);
  bf16* dst = kF + ((size_t)(hh * 64 + kb64) * 8 + t * 2) * 512 + lane * 8;
  *(bf16x8*)(dst)       = *(const bf16x8*)(&sK[row * 72 + quad * 8]);
  *(bf16x8*)(dst + 512) = *(const bf16x8*)(&sK[row * 72 + 32 + quad * 8]);
}

// ---------------- causal flash attention: LDS-free, barrier-free, 2-wave blocks ----------------
// grid (H, 64, 4), block 128 = 2 INDEPENDENT waves; 32 q-rows/wave (two 16-row
// subtiles); 64-key chunks; K/V fragments loaded directly global->VGPR from
// frag-layout kF/vF (each frag = 64 lanes x 16B contiguous). No LDS/barriers.
// R11: small blocks -> 16 blocks/CU co-resident with fine-grained retirement
// and continuous backfill (R10's 2048x256t grid filled capacity exactly once
// and drained -- avg residency 1.5 waves/SIMD, 18% occupancy).
__global__ __launch_bounds__(128) void attn_kernel(const bf16* __restrict__ qkv,
                                                   const bf16* __restrict__ kF,
                                                   const bf16* __restrict__ vF,
                                                   bf16* __restrict__ Opart,
                                                   float* __restrict__ lws) {
  const int hh = blockIdx.x;
  const int qp = (int)(gridDim.y - 1 - blockIdx.y);  // heavy blocks dispatch first
  const int sp = blockIdx.z;
  const int tid = threadIdx.x;
  const int wave = tid >> 6, lane = tid & 63;
  const int col = lane & 15, quad = lane >> 4;
  const int qbase = qp * 64 + wave * 32;

  // Q fragments (B-operand layout) for the two 16-row subtiles
  const bf16* qp0 = qkv + (size_t)(qbase + col) * N3_ + hh * HD_;
  bf16x8 aq[2][2];
  aq[0][0] = *(const bf16x8*)(qp0 + quad * 8);
  aq[0][1] = *(const bf16x8*)(qp0 + 32 + quad * 8);
  aq[1][0] = *(const bf16x8*)(qp0 + 16 * N3_ + quad * 8);
  aq[1][1] = *(const bf16x8*)(qp0 + 16 * N3_ + 32 + quad * 8);

  bf16x8 ones;
#pragma unroll
  for (int j = 0; j < 8; ++j) ones[j] = (bf16)1.0f;

  f32x4 acc[2][4] = {};
  f32x4 acc_l[2] = {};

  const int niter = qp + 1;          // 64-key chunks needed by this block
  const int bse = niter >> 2, rem = niter & 3;
  const int it0 = sp * bse + (sp < rem ? sp : rem);
  const int len = bse + (sp < rem ? 1 : 0);
  const int it1 = it0 + len;

  const bf16* kfp = kF + (size_t)(hh * 64 + it0) * 4096 + lane * 8;
  const bf16* vfp = vF + (size_t)(hh * 64 + it0) * 4096 + lane * 8;

  for (int j = it0; j < it1; ++j, kfp += 4096, vfp += 4096) {
    const int kb = j * 64;
    if (kb >= qbase + 32) break;  // causal: all later chunks masked (wave-uniform)
    const bool act0 = kb < qbase + 16;

    // --- S^T tiles: K-frags direct from kF ---
    f32x4 st[2][4];
#pragma unroll
    for (int t = 0; t < 4; ++t) {
      bf16x8 bk0 = *(const bf16x8*)(kfp + (t * 2) * 512);
      bf16x8 bk1 = *(const bf16x8*)(kfp + (t * 2 + 1) * 512);
      if (act0) {
        f32x4 z = {};
        z = __builtin_amdgcn_mfma_f32_16x16x32_bf16(bk0, aq[0][0], z, 0, 0, 0);
        st[0][t] = __builtin_amdgcn_mfma_f32_16x16x32_bf16(bk1, aq[0][1], z, 0, 0, 0);
      }
      f32x4 z = {};
      z = __builtin_amdgcn_mfma_f32_16x16x32_bf16(bk0, aq[1][0], z, 0, 0, 0);
      st[1][t] = __builtin_amdgcn_mfma_f32_16x16x32_bf16(bk1, aq[1][1], z, 0, 0, 0);
    }

    // --- p = exp2(s); causal mask only on diagonal chunks; perm-pack to bf16 ---
    bf16x8 pfrag[2][2];
#pragma unroll
    for (int s2 = 0; s2 < 2; ++s2) {
      if (s2 == 0 && !act0) continue;
      const int rowbase = qbase + 16 * s2;
      float p[4][4];
      if (kb + 63 <= rowbase) {  // fully unmasked
#pragma unroll
        for (int t = 0; t < 4; ++t)
#pragma unroll
          for (int r = 0; r < 4; ++r)
            p[t][r] = __builtin_amdgcn_exp2f(st[s2][t][r]);
      } else {                   // diagonal: causal mask
#pragma unroll
        for (int t = 0; t < 4; ++t)
#pragma unroll
          for (int r = 0; r < 4; ++r) {
            int key = kb + (t >> 1) * 32 + quad * 8 + (t & 1) * 4 + r;
            p[t][r] = (key > rowbase + col)
                          ? 0.f
                          : __builtin_amdgcn_exp2f(st[s2][t][r]);
          }
      }
#pragma unroll
      for (int c = 0; c < 2; ++c) {
        union { bf16x8 v; u32x4 u; } pu;
        pu.u[0] = __builtin_amdgcn_perm(fbits(p[2 * c][1]),     fbits(p[2 * c][0]),     0x07060302u);
        pu.u[1] = __builtin_amdgcn_perm(fbits(p[2 * c][3]),     fbits(p[2 * c][2]),     0x07060302u);
        pu.u[2] = __builtin_amdgcn_perm(fbits(p[2 * c + 1][1]), fbits(p[2 * c + 1][0]), 0x07060302u);
        pu.u[3] = __builtin_amdgcn_perm(fbits(p[2 * c + 1][3]), fbits(p[2 * c + 1][2]), 0x07060302u);
        pfrag[s2][c] = pu.v;
      }
    }

    // --- PV + l-accumulation: V-frags direct from vF ---
#pragma unroll
    for (int c = 0; c < 2; ++c) {
#pragma unroll
      for (int n = 0; n < 4; ++n) {
        bf16x8 bv = *(const bf16x8*)(vfp + (c * 4 + n) * 512);
        if (act0)
          acc[0][n] = __builtin_amdgcn_mfma_f32_16x16x32_bf16(pfrag[0][c], bv, acc[0][n], 0, 0, 0);
        acc[1][n] = __builtin_amdgcn_mfma_f32_16x16x32_bf16(pfrag[1][c], bv, acc[1][n], 0, 0, 0);
      }
      if (act0)
        acc_l[0] = __builtin_amdgcn_mfma_f32_16x16x32_bf16(pfrag[0][c], ones, acc_l[0], 0, 0, 0);
      acc_l[1] = __builtin_amdgcn_mfma_f32_16x16x32_bf16(pfrag[1][c], ones, acc_l[1], 0, 0, 0);
    }
  }

  // --- epilogue: write unnormalized O partial (bf16) and l partial (f32) ---
  bf16* Op = Opart + (size_t)sp * S_ * D_;
#pragma unroll
  for (int s2 = 0; s2 < 2; ++s2) {
    const int rowbase = qbase + 16 * s2;
    if (col == 0) {
#pragma unroll
      for (int r = 0; r < 4; ++r)
        lws[((size_t)sp * H_ + hh) * S_ + rowbase + quad * 4 + r] = acc_l[s2][r];
    }
#pragma unroll
    for (int n = 0; n < 4; ++n)
#pragma unroll
      for (int r = 0; r < 4; ++r)
        Op[(size_t)(rowbase + quad * 4 + r) * D_ + hh * HD_ + n * 16 + col] =
            (bf16)acc[s2][n][r];
  }
}

// ---------------- combine the four K-split partials ----------------
__global__ __launch_bounds__(256) void attn_combine(const bf16* __restrict__ Opart,
                                                    const float* __restrict__ lws,
                                                    bf16* __restrict__ outb) {
  int e = (blockIdx.x * 256 + threadIdx.x) * 8;
  int s = e >> 10;              // / D_
  int h = (e & (D_ - 1)) >> 6;  // head
  float l = 0.f;
#pragma unroll
  for (int sp = 0; sp < NSPLIT; ++sp) l += lws[((size_t)sp * H_ + h) * S_ + s];
  float inv = 1.0f / l;
  float o[8] = {};
#pragma unroll
  for (int sp = 0; sp < NSPLIT; ++sp) {
    bf16x8 a = *(const bf16x8*)(Opart + (size_t)sp * S_ * D_ + e);
#pragma unroll
    for (int j = 0; j < 8; ++j) o[j] += (float)a[j];
  }
  bf16x8 r;
#pragma unroll
  for (int j = 0; j < 8; ++j) r[j] = (bf16)(o[j] * inv);
  *(bf16x8*)(outb + e) = r;
}

// ---------------- host orchestration ----------------
extern "C" void kernel_launch(void* const* d_in, const int* in_sizes, int n_in,
                              void* d_out, int out_size, void* d_ws, size_t ws_size,
                              hipStream_t stream) {
  const float* x      = (const float*)d_in[0];
  const float* w_qkv  = (const float*)d_in[1];
  const float* b_qkv  = (const float*)d_in[2];
  const float* w_proj = (const float*)d_in[3];
  const float* b_proj = (const float*)d_in[4];
  float* out = (float*)d_out;

  // Buffer overlay (lifetimes verified):
  //   xb: prep->GEMM (x bf16); then repackK->attn (kF); then combine->proj (attn out)
  //   vF: GEMM epilogue writes, attn reads
  bf16* xb     = (bf16*)d_ws;                       // 8 MB  (= kF = attn out)
  bf16* wqkvT  = xb + (size_t)S_ * D_;              // 6 MB
  bf16* wprojT = wqkvT + (size_t)N3_ * D_;          // 2 MB
  bf16* qkv    = wprojT + (size_t)D_ * D_;          // 24 MB (V cols unused)
  bf16* vF     = qkv + (size_t)S_ * N3_;            // 8 MB  frag-layout V
  bf16* Opart  = vF + (size_t)D_ * S_;              // 32 MB
  float* lws   = (float*)(Opart + (size_t)NSPLIT * S_ * D_);  // 1 MB
  bf16* kF     = xb;
  bf16* attn   = xb;

  const float QSCALE = 0.125f * 1.44269504088896f;  // 1/sqrt(64) * log2(e)

  prep_kernel<<<dim3(8192), 256, 0, stream>>>(x, xb, w_qkv, wqkvT, w_proj, wprojT);
  // QKV GEMM; Q cols pre-scaled; V cols written directly in frag layout to vF
  gemm_bt<128><<<dim3(S_ / 128, N3_ / 128), 256, 0, stream>>>(
      xb, wqkvT, b_qkv, qkv, nullptr, vF, S_, N3_, D_, D_, QSCALE);
  repackK<<<dim3(H_, S_ / 64), 256, 0, stream>>>(qkv, kF);
  attn_kernel<<<dim3(H_, S_ / 64, NSPLIT), 128, 0, stream>>>(qkv, kF, vF, Opart, lws);
  attn_combine<<<dim3((S_ * D_) / 2048), 256, 0, stream>>>(Opart, lws, attn);
  // proj GEMM: 128x64 tiles -> 512 blocks (2/CU) for latency hiding
  gemm_bt<64><<<dim3(S_ / 128, D_ / 64), 256, 0, stream>>>(
      attn, wprojT, b_proj, nullptr, out, nullptr, S_, D_, D_, 0, 1.0f);
}

// Round 12
// 214.157 us; speedup vs baseline: 1.0138x; 1.0116x over previous
//
#include <hip/hip_runtime.h>
#include <hip/hip_bf16.h>
#include <math.h>

typedef __bf16 bf16;
typedef __bf16 bf16x8 __attribute__((ext_vector_type(8)));
typedef __bf16 bf16x4 __attribute__((ext_vector_type(4)));
typedef float f32x4 __attribute__((ext_vector_type(4)));
typedef unsigned int u32;
typedef u32 u32x4 __attribute__((ext_vector_type(4)));

#define S_ 4096
#define D_ 1024
#define H_ 16
#define HD_ 64
#define N3_ 3072
#define NSPLIT 4

// async global->LDS 16B (m97 pattern)
typedef const __attribute__((address_space(1))) void* gas1_t;
typedef __attribute__((address_space(3))) void* las3_t;
static __device__ __forceinline__ void g2l16(const void* g, void* l) {
  __builtin_amdgcn_global_load_lds((gas1_t)g, (las3_t)l, 16, 0, 0);
}

static __device__ __forceinline__ u32 fbits(float x) {
  union { float f; u32 u; } c; c.f = x; return c.u;
}

// ---------------- fused prep: cvt x -> bf16, transpose both weights ----------------
__global__ __launch_bounds__(256) void prep_kernel(const float* __restrict__ x,
                                                   bf16* __restrict__ xb,
                                                   const float* __restrict__ w_qkv,
                                                   bf16* __restrict__ wqkvT,
                                                   const float* __restrict__ w_proj,
                                                   bf16* __restrict__ wprojT) {
  __shared__ float t[32][33];
  const int b = blockIdx.x;
  if (b < 4096) {
    int i = (b * 256 + threadIdx.x) * 4;
    float4 v = *(const float4*)(x + i);
    bf16x4 o;
    o.x = (bf16)v.x; o.y = (bf16)v.y; o.z = (bf16)v.z; o.w = (bf16)v.w;
    *(bf16x4*)(xb + i) = o;
    return;
  }
  const float* in; bf16* outp; int ldin, bx, by;
  if (b < 7168) { int b2 = b - 4096; in = w_qkv;  outp = wqkvT;  ldin = N3_; bx = (b2 % 96) * 32; by = (b2 / 96) * 32; }
  else          { int b3 = b - 7168; in = w_proj; outp = wprojT; ldin = D_;  bx = (b3 % 32) * 32; by = (b3 / 32) * 32; }
  const int tx = threadIdx.x & 31, ty = threadIdx.x >> 5;
#pragma unroll
  for (int i = 0; i < 4; ++i)
    t[ty + i * 8][tx] = in[(size_t)(by + ty + i * 8) * ldin + bx + tx];
  __syncthreads();
#pragma unroll
  for (int i = 0; i < 4; ++i)
    outp[(size_t)(bx + ty + i * 8) * D_ + by + tx] = (bf16)t[tx][ty + i * 8];
}

// ---------------- bf16 GEMM (m97 pattern): C = A * Bt^T + bias ----------------
// If vF != nullptr (QKV mode): Q cols scaled by qscale, V cols (gn>=2048)
// written directly in MFMA-fragment layout vF[hh][kb64][c][n][lane][8].
template <int BN>
__global__ __launch_bounds__(256) void gemm_bt(const bf16* __restrict__ A,
                                               const bf16* __restrict__ Bt,
                                               const float* __restrict__ bias,
                                               bf16* __restrict__ outb,
                                               float* __restrict__ outf,
                                               bf16* __restrict__ vF,
                                               int M, int N, int K,
                                               int qlim, float qscale) {
  constexpr int NT = BN / 32;  // n-tiles per wave
  __shared__ bf16 sA[128 * 32];
  __shared__ bf16 sB[BN * 32];
  const int tid = threadIdx.x;
  const int wave = tid >> 6, lane = tid & 63;
  const int col = lane & 15, quad = lane >> 4;
  const int wm = (wave & 1) * 64, wn = (wave >> 1) * (BN / 2);
  const long bm = (long)blockIdx.x * 128, bn = (long)blockIdx.y * BN;
  const int srow = tid >> 2;        // 0..63
  const int soff = (tid & 3) * 8;   // elem in 32-elem row

  f32x4 acc[4][NT] = {};

  for (int kb = 0; kb < K; kb += 32) {
    __syncthreads();
    g2l16(A + (bm + srow) * (long)K + kb + soff,      &sA[tid * 8]);
    g2l16(A + (bm + 64 + srow) * (long)K + kb + soff, &sA[2048 + tid * 8]);
#pragma unroll
    for (int i = 0; i < BN / 64; ++i)
      g2l16(Bt + (bn + i * 64 + srow) * (long)K + kb + soff, &sB[i * 2048 + tid * 8]);
    __syncthreads();

    bf16x8 af[4], bfr[NT];
#pragma unroll
    for (int t = 0; t < 4; ++t)
      af[t] = *(const bf16x8*)(&sA[(wm + t * 16 + col) * 32 + quad * 8]);
#pragma unroll
    for (int t = 0; t < NT; ++t)
      bfr[t] = *(const bf16x8*)(&sB[(wn + t * 16 + col) * 32 + quad * 8]);
#pragma unroll
    for (int mt = 0; mt < 4; ++mt)
#pragma unroll
      for (int nt = 0; nt < NT; ++nt)
        acc[mt][nt] = __builtin_amdgcn_mfma_f32_16x16x32_bf16(af[mt], bfr[nt], acc[mt][nt], 0, 0, 0);
  }

#pragma unroll
  for (int mt = 0; mt < 4; ++mt) {
#pragma unroll
    for (int nt = 0; nt < NT; ++nt) {
      long gn = bn + wn + nt * 16 + col;
      float bv = bias ? bias[gn] : 0.f;
      if (vF && gn >= 2 * D_) {  // V column -> fragment-layout store
        int hd = (int)gn - 2 * D_;
        int hh2 = hd >> 6, nn = (hd >> 4) & 3, colp = hd & 15;
        long key0 = bm + wm + mt * 16 + quad * 4;   // 4-aligned, no 64-crossing
        int kb64 = (int)(key0 >> 6), kl = (int)(key0 & 63);
        int cc = kl >> 5, qp2 = (kl >> 3) & 3, j0 = kl & 7;  // j0 in {0,4}
        bf16x4 vv;
#pragma unroll
        for (int i = 0; i < 4; ++i) vv[i] = (bf16)(acc[mt][nt][i] + bv);
        *(bf16x4*)(&vF[((((size_t)(hh2 * 64 + kb64) * 2 + cc) * 4 + nn) * 64 +
                        qp2 * 16 + colp) * 8 + j0]) = vv;
      } else {
        float sc = (gn < qlim) ? qscale : 1.0f;
#pragma unroll
        for (int i = 0; i < 4; ++i) {
          long gm = bm + wm + mt * 16 + quad * 4 + i;
          float v = (acc[mt][nt][i] + bv) * sc;
          if (outf) outf[gm * N + gn] = v;
          else      outb[gm * N + gn] = (bf16)v;
        }
      }
    }
  }
}

// ---------------- repack K rows -> fragment layout kF ----------------
__global__ __launch_bounds__(256) void repackK(const bf16* __restrict__ qkv,
                                               bf16* __restrict__ kF) {
  __shared__ bf16 sK[64 * 72];
  const int hh = blockIdx.x, kb64 = blockIdx.y;
  const int tid = threadIdx.x;
  const int srow = tid >> 2, sc = (tid & 3) * 16;
  const bf16* src = qkv + (size_t)(kb64 * 64 + srow) * N3_ + D_ + hh * HD_ + sc;
  *(int4*)(&sK[srow * 72 + sc])     = *(const int4*)src;
  *(int4*)(&sK[srow * 72 + sc + 8]) = *(const int4*)(src + 8);
  __syncthreads();
  const int lane = tid & 63, col = lane & 15, quad = lane >> 4;
  const int t = tid >> 6;  // wave = t
  const int row = (t >> 1) * 32 + (t & 1) * 4 + (col >> 2) * 8 + (col & 3);
  bf16* dst = kF + ((size_t)(hh * 64 + kb64) * 8 + t * 2) * 512 + lane * 8;
  *(bf16x8*)(dst)       = *(const bf16x8*)(&sK[row * 72 + quad * 8]);
  *(bf16x8*)(dst + 512) = *(const bf16x8*)(&sK[row * 72 + 32 + quad * 8]);
}

// ---------------- causal flash attention: register-pipelined, LDS/barrier-free ----------------
// grid (H, 64, 4), block 128 = 2 independent waves; 32 q-rows/wave.
// R12: software-pipelined chain. Loop invariant entering iter j: st(j) already
// computed (QK done at end of iter j-1), K(j) consumed. Per iter:
//   issue V(j) loads -> issue K(j+1) loads -> exp/pack(st(j)) [VALU, covers V
//   latency] -> PV(j) [MFMA] -> QK(j+1) from K regs issued ~400 cyc earlier.
// No load is consumed in the iteration that issues it; QK(j+1) overlaps the
// next iter's exp. Masking only at the global diagonal chunk j == qp.
__global__ __launch_bounds__(128) void attn_kernel(const bf16* __restrict__ qkv,
                                                   const bf16* __restrict__ kF,
                                                   const bf16* __restrict__ vF,
                                                   bf16* __restrict__ Opart,
                                                   float* __restrict__ lws) {
  const int hh = blockIdx.x;
  const int qp = (int)(gridDim.y - 1 - blockIdx.y);  // heavy blocks dispatch first
  const int sp = blockIdx.z;
  const int tid = threadIdx.x;
  const int wave = tid >> 6, lane = tid & 63;
  const int col = lane & 15, quad = lane >> 4;
  const int qbase = qp * 64 + wave * 32;

  // Q fragments (B-operand layout) for the two 16-row subtiles
  const bf16* qp0 = qkv + (size_t)(qbase + col) * N3_ + hh * HD_;
  bf16x8 aq[2][2];
  aq[0][0] = *(const bf16x8*)(qp0 + quad * 8);
  aq[0][1] = *(const bf16x8*)(qp0 + 32 + quad * 8);
  aq[1][0] = *(const bf16x8*)(qp0 + 16 * N3_ + quad * 8);
  aq[1][1] = *(const bf16x8*)(qp0 + 16 * N3_ + 32 + quad * 8);

  bf16x8 ones;
#pragma unroll
  for (int j = 0; j < 8; ++j) ones[j] = (bf16)1.0f;

  f32x4 acc[2][4] = {};
  f32x4 acc_l[2] = {};

  const int niter = qp + 1;          // 64-key chunks needed by this block
  const int bse = niter >> 2, rem = niter & 3;
  const int it0 = sp * bse + (sp < rem ? sp : rem);
  const int len = bse + (sp < rem ? 1 : 0);
  const int it1 = it0 + len;

  if (len > 0) {
    const bf16* kfp = kF + (size_t)(hh * 64 + it0) * 4096 + lane * 8;
    const bf16* vfp = vF + (size_t)(hh * 64 + it0) * 4096 + lane * 8;

    // ---- prologue: load K(it0), compute st(it0) ----
    bf16x8 bk[8];
#pragma unroll
    for (int t = 0; t < 8; ++t) bk[t] = *(const bf16x8*)(kfp + t * 512);
    kfp += 4096;

    f32x4 st[2][4];
#pragma unroll
    for (int t = 0; t < 4; ++t) {
      f32x4 z = {};
      z = __builtin_amdgcn_mfma_f32_16x16x32_bf16(bk[2 * t], aq[0][0], z, 0, 0, 0);
      st[0][t] = __builtin_amdgcn_mfma_f32_16x16x32_bf16(bk[2 * t + 1], aq[0][1], z, 0, 0, 0);
      f32x4 z2 = {};
      z2 = __builtin_amdgcn_mfma_f32_16x16x32_bf16(bk[2 * t], aq[1][0], z2, 0, 0, 0);
      st[1][t] = __builtin_amdgcn_mfma_f32_16x16x32_bf16(bk[2 * t + 1], aq[1][1], z2, 0, 0, 0);
    }

    for (int j = it0; j < it1; ++j) {
      const bool more = (j + 1 < it1);
      const int kb = j * 64;

      // issue V(j) loads (consumed after exp -- latency covered by VALU)
      bf16x8 bv[8];
#pragma unroll
      for (int t = 0; t < 8; ++t) bv[t] = *(const bf16x8*)(vfp + t * 512);
      vfp += 4096;

      // issue K(j+1) loads (consumed at end of this iter by QK)
      if (more) {
#pragma unroll
        for (int t = 0; t < 8; ++t) bk[t] = *(const bf16x8*)(kfp + t * 512);
        kfp += 4096;
      }

      // --- exp/pack from st(j); mask only on the global diagonal chunk ---
      bf16x8 pfrag[2][2];
      if (j == qp) {  // diagonal chunk (wave-uniform)
#pragma unroll
        for (int s2 = 0; s2 < 2; ++s2) {
          const int rowbase = qbase + 16 * s2;
          float p[4][4];
#pragma unroll
          for (int t = 0; t < 4; ++t)
#pragma unroll
            for (int r = 0; r < 4; ++r) {
              int key = kb + (t >> 1) * 32 + quad * 8 + (t & 1) * 4 + r;
              p[t][r] = (key > rowbase + col)
                            ? 0.f
                            : __builtin_amdgcn_exp2f(st[s2][t][r]);
            }
#pragma unroll
          for (int c = 0; c < 2; ++c) {
            union { bf16x8 v; u32x4 u; } pu;
            pu.u[0] = __builtin_amdgcn_perm(fbits(p[2 * c][1]),     fbits(p[2 * c][0]),     0x07060302u);
            pu.u[1] = __builtin_amdgcn_perm(fbits(p[2 * c][3]),     fbits(p[2 * c][2]),     0x07060302u);
            pu.u[2] = __builtin_amdgcn_perm(fbits(p[2 * c + 1][1]), fbits(p[2 * c + 1][0]), 0x07060302u);
            pu.u[3] = __builtin_amdgcn_perm(fbits(p[2 * c + 1][3]), fbits(p[2 * c + 1][2]), 0x07060302u);
            pfrag[s2][c] = pu.v;
          }
        }
      } else {
#pragma unroll
        for (int s2 = 0; s2 < 2; ++s2) {
          float p[4][4];
#pragma unroll
          for (int t = 0; t < 4; ++t)
#pragma unroll
            for (int r = 0; r < 4; ++r)
              p[t][r] = __builtin_amdgcn_exp2f(st[s2][t][r]);
#pragma unroll
          for (int c = 0; c < 2; ++c) {
            union { bf16x8 v; u32x4 u; } pu;
            pu.u[0] = __builtin_amdgcn_perm(fbits(p[2 * c][1]),     fbits(p[2 * c][0]),     0x07060302u);
            pu.u[1] = __builtin_amdgcn_perm(fbits(p[2 * c][3]),     fbits(p[2 * c][2]),     0x07060302u);
            pu.u[2] = __builtin_amdgcn_perm(fbits(p[2 * c + 1][1]), fbits(p[2 * c + 1][0]), 0x07060302u);
            pu.u[3] = __builtin_amdgcn_perm(fbits(p[2 * c + 1][3]), fbits(p[2 * c + 1][2]), 0x07060302u);
            pfrag[s2][c] = pu.v;
          }
        }
      }

      // --- PV + l (MFMA; waits on V(j) issued this iter) ---
#pragma unroll
      for (int c = 0; c < 2; ++c) {
#pragma unroll
        for (int n = 0; n < 4; ++n) {
          acc[0][n] = __builtin_amdgcn_mfma_f32_16x16x32_bf16(pfrag[0][c], bv[c * 4 + n], acc[0][n], 0, 0, 0);
          acc[1][n] = __builtin_amdgcn_mfma_f32_16x16x32_bf16(pfrag[1][c], bv[c * 4 + n], acc[1][n], 0, 0, 0);
        }
        acc_l[0] = __builtin_amdgcn_mfma_f32_16x16x32_bf16(pfrag[0][c], ones, acc_l[0], 0, 0, 0);
        acc_l[1] = __builtin_amdgcn_mfma_f32_16x16x32_bf16(pfrag[1][c], ones, acc_l[1], 0, 0, 0);
      }

      // --- QK(j+1) from K regs issued at top of this iter ---
      if (more) {
#pragma unroll
        for (int t = 0; t < 4; ++t) {
          f32x4 z = {};
          z = __builtin_amdgcn_mfma_f32_16x16x32_bf16(bk[2 * t], aq[0][0], z, 0, 0, 0);
          st[0][t] = __builtin_amdgcn_mfma_f32_16x16x32_bf16(bk[2 * t + 1], aq[0][1], z, 0, 0, 0);
          f32x4 z2 = {};
          z2 = __builtin_amdgcn_mfma_f32_16x16x32_bf16(bk[2 * t], aq[1][0], z2, 0, 0, 0);
          st[1][t] = __builtin_amdgcn_mfma_f32_16x16x32_bf16(bk[2 * t + 1], aq[1][1], z2, 0, 0, 0);
        }
      }
    }
  }

  // --- epilogue: write unnormalized O partial (bf16) and l partial (f32) ---
  bf16* Op = Opart + (size_t)sp * S_ * D_;
#pragma unroll
  for (int s2 = 0; s2 < 2; ++s2) {
    const int rowbase = qbase + 16 * s2;
    if (col == 0) {
#pragma unroll
      for (int r = 0; r < 4; ++r)
        lws[((size_t)sp * H_ + hh) * S_ + rowbase + quad * 4 + r] = acc_l[s2][r];
    }
#pragma unroll
    for (int n = 0; n < 4; ++n)
#pragma unroll
      for (int r = 0; r < 4; ++r)
        Op[(size_t)(rowbase + quad * 4 + r) * D_ + hh * HD_ + n * 16 + col] =
            (bf16)acc[s2][n][r];
  }
}

// ---------------- combine the four K-split partials ----------------
__global__ __launch_bounds__(256) void attn_combine(const bf16* __restrict__ Opart,
                                                    const float* __restrict__ lws,
                                                    bf16* __restrict__ outb) {
  int e = (blockIdx.x * 256 + threadIdx.x) * 8;
  int s = e >> 10;              // / D_
  int h = (e & (D_ - 1)) >> 6;  // head
  float l = 0.f;
#pragma unroll
  for (int sp = 0; sp < NSPLIT; ++sp) l += lws[((size_t)sp * H_ + h) * S_ + s];
  float inv = 1.0f / l;
  float o[8] = {};
#pragma unroll
  for (int sp = 0; sp < NSPLIT; ++sp) {
    bf16x8 a = *(const bf16x8*)(Opart + (size_t)sp * S_ * D_ + e);
#pragma unroll
    for (int j = 0; j < 8; ++j) o[j] += (float)a[j];
  }
  bf16x8 r;
#pragma unroll
  for (int j = 0; j < 8; ++j) r[j] = (bf16)(o[j] * inv);
  *(bf16x8*)(outb + e) = r;
}

// ---------------- host orchestration ----------------
extern "C" void kernel_launch(void* const* d_in, const int* in_sizes, int n_in,
                              void* d_out, int out_size, void* d_ws, size_t ws_size,
                              hipStream_t stream) {
  const float* x      = (const float*)d_in[0];
  const float* w_qkv  = (const float*)d_in[1];
  const float* b_qkv  = (const float*)d_in[2];
  const float* w_proj = (const float*)d_in[3];
  const float* b_proj = (const float*)d_in[4];
  float* out = (float*)d_out;

  // Buffer overlay (lifetimes verified):
  //   xb: prep->GEMM (x bf16); then repackK->attn (kF); then combine->proj (attn out)
  //   vF: GEMM epilogue writes, attn reads
  bf16* xb     = (bf16*)d_ws;                       // 8 MB  (= kF = attn out)
  bf16* wqkvT  = xb + (size_t)S_ * D_;              // 6 MB
  bf16* wprojT = wqkvT + (size_t)N3_ * D_;          // 2 MB
  bf16* qkv    = wprojT + (size_t)D_ * D_;          // 24 MB (V cols unused)
  bf16* vF     = qkv + (size_t)S_ * N3_;            // 8 MB  frag-layout V
  bf16* Opart  = vF + (size_t)D_ * S_;              // 32 MB
  float* lws   = (float*)(Opart + (size_t)NSPLIT * S_ * D_);  // 1 MB
  bf16* kF     = xb;
  bf16* attn   = xb;

  const float QSCALE = 0.125f * 1.44269504088896f;  // 1/sqrt(64) * log2(e)

  prep_kernel<<<dim3(8192), 256, 0, stream>>>(x, xb, w_qkv, wqkvT, w_proj, wprojT);
  // QKV GEMM; Q cols pre-scaled; V cols written directly in frag layout to vF
  gemm_bt<128><<<dim3(S_ / 128, N3_ / 128), 256, 0, stream>>>(
      xb, wqkvT, b_qkv, qkv, nullptr, vF, S_, N3_, D_, D_, QSCALE);
  repackK<<<dim3(H_, S_ / 64), 256, 0, stream>>>(qkv, kF);
  attn_kernel<<<dim3(H_, S_ / 64, NSPLIT), 128, 0, stream>>>(qkv, kF, vF, Opart, lws);
  attn_combine<<<dim3((S_ * D_) / 2048), 256, 0, stream>>>(Opart, lws, attn);
  // proj GEMM: 128x64 tiles -> 512 blocks (2/CU) for latency hiding
  gemm_bt<64><<<dim3(S_ / 128, D_ / 64), 256, 0, stream>>>(
      attn, wprojT, b_proj, nullptr, out, nullptr, S_, D_, D_, 0, 1.0f);
}